// Round 3
// baseline (2553.201 us; speedup 1.0000x reference)
//
#include <hip/hip_runtime.h>
#include <cstdint>
#include <cstddef>

// ---------------------------------------------------------------------------
// SiGNN forward, MI355X — channel-sequential, compact workspace (~457 MB).
// Per channel c: Z_c = x @ W1[c]^T (100000 x 1024 bf16, one MFMA GEMM), then
// for each active t: gather/mean/BLIF kernel (layer 1) + small fused MFMA
// GEMM with BLIF2 + temporal-pool accumulation (layer 2). Final 128->40 proj.
// ---------------------------------------------------------------------------

typedef unsigned short u16;
typedef u16   u16x8 __attribute__((ext_vector_type(8)));
typedef u16   u16x4 __attribute__((ext_vector_type(4)));
typedef short s16x8 __attribute__((ext_vector_type(8)));
typedef float f32x4 __attribute__((ext_vector_type(4)));

#define NV   100000
#define NF   512
#define NN   16384
#define NC   40
#define NR1  98304   // NN*(1+S1)
#define ZC   1024    // one channel: 4 mats * 256

// workspace layout (bytes, 16-aligned), total 478,920,704
static constexpr size_t OFF_XB   = 0;           // 100000*512*2   = 102,400,000
static constexpr size_t OFF_B1T  = 102400000;   // 3072*512*2     =   3,145,728
static constexpr size_t OFF_B2T  = 105545728;   // 3*256*512*2    =     786,432
static constexpr size_t OFF_SM   = 106332160;   //                      16,384
static constexpr size_t OFF_Z    = 106348544;   // 100000*1024*2  = 204,800,000
static constexpr size_t OFF_V1   = 311148544;   // 98304*256*4    = 100,663,296
static constexpr size_t OFF_V2   = 411811840;   // 16384*128*4    =   8,388,608
static constexpr size_t OFF_EACC = 420200448;   // 16384*128*4    =   8,388,608
static constexpr size_t OFF_OUTS = 428589056;   // 98304*256*2    =  50,331,648
static constexpr size_t OFF_END  = 478920704;
// sm float offsets: bx1@0(768) bt1@768 sigw1@1536 bx2@2304(384) bt2@2688 sigw2@3072 pbsum@3456(128)

__device__ __forceinline__ float b2f(u16 u) { return __uint_as_float(((unsigned)u) << 16); }
__device__ __forceinline__ u16 f2b(float f) {
  unsigned x = __float_as_uint(f);
  unsigned r = (x + 0x7FFFu + ((x >> 16) & 1u)) >> 16;
  return (u16)r;
}
__device__ __forceinline__ float sigm(float x) { return 1.0f / (1.0f + __expf(-x)); }

__device__ __forceinline__ void gload_lds16(const void* g, void* l) {
  __builtin_amdgcn_global_load_lds((const __attribute__((address_space(1))) unsigned*)g,
                                   (__attribute__((address_space(3))) unsigned*)l, 16, 0, 0);
}

// -------------------------------- prep -------------------------------------

__global__ __launch_bounds__(256) void k_zero(float* __restrict__ p, int n4) {
  const int stride = gridDim.x * 256;
  for (int i = blockIdx.x * 256 + threadIdx.x; i < n4; i += stride) {
    f32x4 z = {0.f, 0.f, 0.f, 0.f};
    reinterpret_cast<f32x4*>(p)[i] = z;
  }
}

__global__ __launch_bounds__(256) void k_cast(const float* __restrict__ in, u16* __restrict__ out, int n4) {
  int i = blockIdx.x * 256 + threadIdx.x;
  if (i >= n4) return;
  f32x4 v = reinterpret_cast<const f32x4*>(in)[i];
  u16x4 o;
  o[0] = f2b(v[0]); o[1] = f2b(v[1]); o[2] = f2b(v[2]); o[3] = f2b(v[3]);
  reinterpret_cast<u16x4*>(out)[i] = o;
}

// b2t[c][n'][k]: n'=p*128+h; p=0: x-path (q=0 self k<256, q=1 neigh k>=256); p=1: t-path (q=2/3)
__global__ __launch_bounds__(256) void k_b2t(const float* __restrict__ a2w, u16* __restrict__ b2t) {
  int idx = blockIdx.x * 256 + threadIdx.x;   // < 393216
  int c = idx / 131072; int rem = idx & 131071;
  int hp = rem >> 9; int k = rem & 511;
  int p = hp >> 7, h = hp & 127;
  int q = 2 * p + (k >= 256 ? 1 : 0);
  int kk = k & 255;
  b2t[idx] = f2b(a2w[(((c * 4 + q) * 128) + h) * 256 + kk]);
}

__global__ __launch_bounds__(256) void k_small(const float* __restrict__ a1b, const float* __restrict__ a2b,
    const float* __restrict__ s1w, const float* __restrict__ s2w,
    const float* __restrict__ pb1, const float* __restrict__ pb2, const float* __restrict__ pb3,
    float* __restrict__ sm) {
  int i = blockIdx.x * 256 + threadIdx.x;
  if (i < 768) {
    int c = i >> 8, j = i & 255;
    sm[i]        = a1b[(c * 4 + 0) * 256 + j] + a1b[(c * 4 + 1) * 256 + j];
    sm[768 + i]  = a1b[(c * 4 + 2) * 256 + j] + a1b[(c * 4 + 3) * 256 + j];
    sm[1536 + i] = sigm(s1w[i]);
  } else if (i < 1152) {
    int i2 = i - 768; int c = i2 >> 7, h = i2 & 127;
    sm[2304 + i2] = a2b[(c * 4 + 0) * 128 + h] + a2b[(c * 4 + 1) * 128 + h];
    sm[2688 + i2] = a2b[(c * 4 + 2) * 128 + h] + a2b[(c * 4 + 3) * 128 + h];
    sm[3072 + i2] = sigm(s2w[i2]);
  } else if (i < 1280) {
    int h = i - 1152;
    sm[3456 + h] = pb1[h] + pb2[h] + pb3[h];
  }
}

// ------------------------------ Z GEMM (one channel) -----------------------
// Z[M=100000][1024] = xb[M][512] @ Bc[1024][512]^T   (both row-major [i][k])
// 128x128 tile, BK=64, 4 waves (2x2), global_load_lds w=16, XOR-swizzled LDS.

__global__ __launch_bounds__(256) void k_zgemm(const u16* __restrict__ A, const u16* __restrict__ B,
                                               u16* __restrict__ Zo) {
  __shared__ u16 As[128 * 64];
  __shared__ u16 Bs[128 * 64];
  const int tid = threadIdx.x;
  const int wid = tid >> 6, lane = tid & 63;
  const int n0 = blockIdx.x * 128;   // 8 col tiles
  const int m0 = blockIdx.y * 128;
  const int wm = (wid >> 1) * 64, wn = (wid & 1) * 64;
  f32x4 acc[4][4] = {};
  for (int kt = 0; kt < NF; kt += 64) {
#pragma unroll
    for (int i = 0; i < 4; ++i) {
      const int chunk = (i * 4 + wid) * 64 + lane;
      const int row = chunk >> 3;
      const int slot = chunk & 7;
      const int sb = (slot << 4) ^ ((row & 7) << 4);   // inverse-swizzled source offset
      int arow = m0 + row; arow = arow < NV ? arow : (NV - 1);
      const char* ga = (const char*)(A + (size_t)arow * NF + kt) + sb;
      const char* gb = (const char*)(B + (size_t)(n0 + row) * NF + kt) + sb;
      gload_lds16(ga, As + (i * 4 + wid) * 512);
      gload_lds16(gb, Bs + (i * 4 + wid) * 512);
    }
    asm volatile("s_waitcnt vmcnt(0)" ::: "memory");
    __syncthreads();
#pragma unroll
    for (int ks = 0; ks < 2; ++ks) {
      s16x8 af[4], bfr[4];
#pragma unroll
      for (int i = 0; i < 4; ++i) {
        const int ar = wm + i * 16 + (lane & 15);
        const int kb = ks * 64 + ((lane >> 4) << 4);
        af[i] = __builtin_bit_cast(s16x8,
            *(const u16x8*)((const char*)As + ar * 128 + (kb ^ ((ar & 7) << 4))));
        const int br = wn + i * 16 + (lane & 15);
        bfr[i] = __builtin_bit_cast(s16x8,
            *(const u16x8*)((const char*)Bs + br * 128 + (kb ^ ((br & 7) << 4))));
      }
#pragma unroll
      for (int mi = 0; mi < 4; ++mi)
#pragma unroll
        for (int ni = 0; ni < 4; ++ni)
          acc[mi][ni] = __builtin_amdgcn_mfma_f32_16x16x32_bf16(af[mi], bfr[ni], acc[mi][ni], 0, 0, 0);
    }
    __syncthreads();
  }
#pragma unroll
  for (int mi = 0; mi < 4; ++mi)
#pragma unroll
    for (int ni = 0; ni < 4; ++ni)
#pragma unroll
      for (int r = 0; r < 4; ++r) {
        const int row = m0 + wm + mi * 16 + (lane >> 4) * 4 + r;
        const int col = n0 + wn + ni * 16 + (lane & 15);
        if (row < NV) Zo[(size_t)row * ZC + col] = f2b(acc[mi][ni][r]);
      }
}

// ------------------------- layer-1 fused (per t, per channel) --------------
// one wave per row; lanes cover 256 cols (4 each). Z is one channel [NV][1024].
__global__ __launch_bounds__(256) void k_l1(const u16* __restrict__ Z, const int* __restrict__ nodes,
    const int* __restrict__ n1t, const int* __restrict__ n2t,
    float* __restrict__ v1, u16* __restrict__ outS, const float* __restrict__ sm,
    int c) {
  const int r = blockIdx.x * 4 + (threadIdx.x >> 6);
  const int lane = threadIdx.x & 63;
  const int j = lane * 4;

  int vs, nb[5], ns; float inv;
  if (r < NN) {
    vs = nodes[r]; ns = 5; inv = 0.2f;
    const int* p = n1t + r * 5;
#pragma unroll
    for (int s = 0; s < 5; ++s) nb[s] = p[s];
  } else {
    const int rr = r - NN;
    vs = n1t[rr]; ns = 2; inv = 0.5f;
    nb[0] = n2t[rr * 2]; nb[1] = n2t[rr * 2 + 1];
  }
  const size_t zb = (size_t)vs * ZC;
  const u16x4 sx = *(const u16x4*)(Z + zb + j);         // q=0 self x-path
  const u16x4 st = *(const u16x4*)(Z + zb + 512 + j);   // q=2 self t-path
  float nx[4] = {0.f, 0.f, 0.f, 0.f}, nt[4] = {0.f, 0.f, 0.f, 0.f};
  for (int s = 0; s < ns; ++s) {
    const size_t zn = (size_t)nb[s] * ZC;
    const u16x4 qx = *(const u16x4*)(Z + zn + 256 + j); // q=1 neigh x-path
    const u16x4 qt = *(const u16x4*)(Z + zn + 768 + j); // q=3 neigh t-path
#pragma unroll
    for (int e = 0; e < 4; ++e) { nx[e] += b2f(qx[e]); nt[e] += b2f(qt[e]); }
  }
  const f32x4 bx = *(const f32x4*)(sm + c * 256 + j);
  const f32x4 bt = *(const f32x4*)(sm + 768 + c * 256 + j);
  const f32x4 sw = *(const f32x4*)(sm + 1536 + c * 256 + j);
  const size_t vo = (size_t)r * 256 + j;
  f32x4 vold = *(const f32x4*)(v1 + vo);
  f32x4 vnew; u16x4 os;
#pragma unroll
  for (int e = 0; e < 4; ++e) {
    const float ox = b2f(sx[e]) + nx[e] * inv + bx[e];
    const float ot = b2f(st[e]) + nt[e] * inv + bt[e];
    const float v = sw[e] * vold[e] + ot;
    const float s = (v >= 1.0f) ? 1.0f : 0.0f;
    vnew[e] = v - s;
    os[e] = f2b(s * sigm(ox));
  }
  *(f32x4*)(v1 + vo) = vnew;
  *(u16x4*)(outS + (size_t)r * 256 + j) = os;
}

// ------------------------- layer-2 fused (per t, per channel) --------------
// per block: 16 nodes x 256 outputs; A=[h0b | mean5(h1b)] staged in LDS (swizzled);
// B read direct from global (L2-hot); epilogue: BLIF2 + pool accumulation.
__global__ __launch_bounds__(256) void k_l2(const u16* __restrict__ outS, const u16* __restrict__ B2t,
    float* __restrict__ v2, float* __restrict__ eacc, const float* __restrict__ sm,
    const float* __restrict__ pw, int Tc, int tix, int c) {
  __shared__ u16 As[16 * 512];
  const int tid = threadIdx.x, lane = tid & 63, w = tid >> 6;
  const int n0 = blockIdx.x * 16;
  {
    const int row = tid >> 4;
    const int k0 = (tid & 15) * 32;
#pragma unroll
    for (int g = 0; g < 4; ++g) {
      const int k = k0 + g * 8;
      u16x8 pk;
      if (k < 256) {
        pk = *(const u16x8*)(outS + (size_t)(n0 + row) * 256 + k);
      } else {
        float a[8] = {0.f,0.f,0.f,0.f,0.f,0.f,0.f,0.f};
#pragma unroll
        for (int s = 0; s < 5; ++s) {
          const u16x8 q = *(const u16x8*)(outS + (size_t)(NN + (size_t)(n0 + row) * 5 + s) * 256 + (k - 256));
#pragma unroll
          for (int e = 0; e < 8; ++e) a[e] += b2f(q[e]);
        }
#pragma unroll
        for (int e = 0; e < 8; ++e) pk[e] = f2b(a[e] * 0.2f);
      }
      *(u16x8*)((char*)As + row * 1024 + ((k * 2) ^ ((row & 7) << 4))) = pk;
    }
  }
  __syncthreads();
  const u16* Bc = B2t + (size_t)c * 256 * 512;
  f32x4 acc[4] = {};
  const int nbase[4] = {32 * w, 32 * w + 16, 128 + 32 * w, 128 + 32 * w + 16};
#pragma unroll
  for (int ks = 0; ks < 16; ++ks) {
    const int ar = lane & 15;
    const int kb = ks * 64 + ((lane >> 4) << 4);
    const s16x8 af = __builtin_bit_cast(s16x8,
        *(const u16x8*)((const char*)As + ar * 1024 + (kb ^ ((ar & 7) << 4))));
#pragma unroll
    for (int f = 0; f < 4; ++f) {
      const u16* bp = Bc + (size_t)(nbase[f] + (lane & 15)) * 512 + ks * 32 + ((lane >> 4) << 3);
      const s16x8 bv = __builtin_bit_cast(s16x8, *(const u16x8*)bp);
      acc[f] = __builtin_amdgcn_mfma_f32_16x16x32_bf16(af, bv, acc[f], 0, 0, 0);
    }
  }
  const float* bx2 = sm + 2304 + c * 128;
  const float* bt2 = sm + 2688 + c * 128;
  const float* sw2 = sm + 3072 + c * 128;
#pragma unroll
  for (int f = 0; f < 2; ++f) {
    const int h = 32 * w + 16 * f + (lane & 15);
    const float pwv = pw[h * Tc + tix];
    const float bxv = bx2[h], btv = bt2[h], swv = sw2[h];
#pragma unroll
    for (int r = 0; r < 4; ++r) {
      const int n = n0 + (lane >> 4) * 4 + r;
      const float ox = acc[f][r] + bxv;
      const float ot = acc[f + 2][r] + btv;
      const float v = swv * v2[(size_t)n * 128 + h] + ot;
      const float s = (v >= 1.0f) ? 1.0f : 0.0f;
      v2[(size_t)n * 128 + h] = v - s;
      if (s > 0.0f) eacc[(size_t)n * 128 + h] += sigm(ox) * pwv;
    }
  }
}

// ------------------------------- final -------------------------------------
__global__ __launch_bounds__(256) void k_final(const float* __restrict__ eacc, const float* __restrict__ sm,
    const float* __restrict__ mtgw, const float* __restrict__ mtgb, float* __restrict__ out) {
  const int idx = blockIdx.x * 256 + threadIdx.x;   // exactly 16384*40
  const int n = idx / NC, k = idx % NC;
  const float* e0 = eacc + (size_t)n * 128;
  const float* pb = sm + 3456;
  const float* mw = mtgw + k * 128;
  float accv = 0.0f;
  for (int h = 0; h < 128; ++h) {
    const float emb = (e0[h] + pb[h]) * (1.0f / 3.0f);
    accv += emb * mw[h];
  }
  out[idx] = accv + mtgb[k];
}

// ------------------------------- launch ------------------------------------
extern "C" void kernel_launch(void* const* d_in, const int* in_sizes, int n_in,
                              void* d_out, int out_size, void* d_ws, size_t ws_size,
                              hipStream_t stream) {
  (void)in_sizes; (void)n_in; (void)out_size;
  if (ws_size < OFF_END) return;   // diagnostic guard: mismatch (not crash) if ws too small

  const float* x    = (const float*)d_in[0];
  const float* a1w  = (const float*)d_in[1];
  const float* a1b  = (const float*)d_in[2];
  const float* a2w  = (const float*)d_in[3];
  const float* a2b  = (const float*)d_in[4];
  const float* s1w  = (const float*)d_in[5];
  const float* s2w  = (const float*)d_in[6];
  const float* pw1  = (const float*)d_in[7];
  const float* pb1  = (const float*)d_in[8];
  const float* pw2  = (const float*)d_in[9];
  const float* pb2  = (const float*)d_in[10];
  const float* pw3  = (const float*)d_in[11];
  const float* pb3  = (const float*)d_in[12];
  const float* mtgw = (const float*)d_in[13];
  const float* mtgb = (const float*)d_in[14];
  const int* nodes  = (const int*)d_in[15];
  const int* nbr1   = (const int*)d_in[16];
  const int* nbr2   = (const int*)d_in[17];

  char* w = (char*)d_ws;
  u16* xb    = (u16*)(w + OFF_XB);
  u16* b1t   = (u16*)(w + OFF_B1T);
  u16* b2t   = (u16*)(w + OFF_B2T);
  float* sm  = (float*)(w + OFF_SM);
  u16* z     = (u16*)(w + OFF_Z);
  float* v1  = (float*)(w + OFF_V1);
  float* v2  = (float*)(w + OFF_V2);
  float* eacc= (float*)(w + OFF_EACC);
  u16* outS  = (u16*)(w + OFF_OUTS);

  k_cast<<<50000, 256, 0, stream>>>(x, xb, 12800000);
  k_cast<<<1536, 256, 0, stream>>>(a1w, b1t, 393216);
  k_b2t<<<1536, 256, 0, stream>>>(a2w, b2t);
  k_small<<<5, 256, 0, stream>>>(a1b, a2b, s1w, s2w, pb1, pb2, pb3, sm);
  k_zero<<<512, 256, 0, stream>>>(eacc, 524288);

  // per-channel schedule: active (t, tix) pairs
  static const int nact[3] = {6, 3, 2};
  static const int act_t[3][6]   = {{0,1,2,3,4,5},{0,2,4,-1,-1,-1},{2,5,-1,-1,-1,-1}};
  static const int Tcs[3] = {6, 3, 2};
  const float* pws[3] = {pw1, pw2, pw3};

  for (int c = 0; c < 3; ++c) {
    // zero v1 (+ contiguous v2): (100663296+8388608)/16 bytes = 6815744 f32x4
    k_zero<<<2048, 256, 0, stream>>>(v1, 6815744);
    k_zgemm<<<dim3(8, 782), 256, 0, stream>>>(xb, b1t + (size_t)c * 1024 * 512, z);
    for (int a = 0; a < nact[c]; ++a) {
      const int t = act_t[c][a];
      const int* n1t = nbr1 + t * (NN * 5);
      const int* n2t = nbr2 + t * (NN * 10);
      k_l1<<<24576, 256, 0, stream>>>(z, nodes, n1t, n2t, v1, outS, sm, c);
      k_l2<<<1024, 256, 0, stream>>>(outS, b2t, v2, eacc, sm, pws[c], Tcs[c], a, c);
    }
  }
  k_final<<<2560, 256, 0, stream>>>(eacc, sm, mtgw, mtgb, (float*)d_out);
}

// Round 6
// 2105.867 us; speedup vs baseline: 1.2124x; 1.2124x over previous
//
#include <hip/hip_runtime.h>
#include <cstdint>
#include <cstddef>

// ---------------------------------------------------------------------------
// SiGNN forward, MI355X — channel-sequential, t-fused, ~477 MB workspace.
// Per channel c: Z_c = x @ W1[c]^T (100000 x 1024 bf16, MFMA GEMM, f32 A
// converted in-kernel). Then ONE fused layer-1 launch per t-group (v1 in
// registers across steps) + ONE fused layer-2 launch per group (v2/eacc in
// registers). Final 128->40 projection.
// ---------------------------------------------------------------------------

typedef unsigned short u16;
typedef u16   u16x8 __attribute__((ext_vector_type(8)));
typedef u16   u16x4 __attribute__((ext_vector_type(4)));
typedef short s16x8 __attribute__((ext_vector_type(8)));
typedef float f32x4 __attribute__((ext_vector_type(4)));

#define NV   100000
#define NF   512
#define NN   16384
#define NC   40
#define NR1  98304            // NN*(1+S1)
#define ZC   1024             // one channel: 4 mats * 256
#define SLICE 25165824        // NR1*256 u16 elems per outS slice

// workspace layout (bytes, 256-aligned), total 477,184,000
static constexpr size_t OFF_B1T  = 0;            // 3072*512*2     =   3,145,728
static constexpr size_t OFF_B2T  = 3145728;      // 3*256*512*2    =     786,432
static constexpr size_t OFF_SM   = 3932160;      //                      16,384
static constexpr size_t OFF_Z    = 3948544;      // 100000*1024*2  = 204,800,000
static constexpr size_t OFF_V1   = 208748544;    // 98304*256*4    = 100,663,296
static constexpr size_t OFF_V2   = 309411840;    // 16384*128*4    =   8,388,608
static constexpr size_t OFF_EACC = 317800448;    // 16384*128*4    =   8,388,608
static constexpr size_t OFF_OUTS = 326189056;    // 3*98304*256*2  = 150,994,944
static constexpr size_t OFF_END  = 477184000;
// sm float offsets: bx1@0(768) bt1@768 sigw1@1536 bx2@2304(384) bt2@2688 sigw2@3072 pbsum@3456(128)

__device__ __forceinline__ float b2f(u16 u) { return __uint_as_float(((unsigned)u) << 16); }
__device__ __forceinline__ u16 f2b(float f) {
  unsigned x = __float_as_uint(f);
  unsigned r = (x + 0x7FFFu + ((x >> 16) & 1u)) >> 16;
  return (u16)r;
}
__device__ __forceinline__ float sigm(float x) { return 1.0f / (1.0f + __expf(-x)); }

__device__ __forceinline__ void gload_lds16(const void* g, void* l) {
  __builtin_amdgcn_global_load_lds((const __attribute__((address_space(1))) unsigned*)g,
                                   (__attribute__((address_space(3))) unsigned*)l, 16, 0, 0);
}

// -------------------------------- prep -------------------------------------

__global__ __launch_bounds__(256) void k_zero(float* __restrict__ p, int n4) {
  const int stride = gridDim.x * 256;
  for (int i = blockIdx.x * 256 + threadIdx.x; i < n4; i += stride) {
    f32x4 z = {0.f, 0.f, 0.f, 0.f};
    reinterpret_cast<f32x4*>(p)[i] = z;
  }
}

__global__ __launch_bounds__(256) void k_cast(const float* __restrict__ in, u16* __restrict__ out, int n4) {
  int i = blockIdx.x * 256 + threadIdx.x;
  if (i >= n4) return;
  f32x4 v = reinterpret_cast<const f32x4*>(in)[i];
  u16x4 o;
  o[0] = f2b(v[0]); o[1] = f2b(v[1]); o[2] = f2b(v[2]); o[3] = f2b(v[3]);
  reinterpret_cast<u16x4*>(out)[i] = o;
}

// b2t[c][n'][k]: n'=p*128+h; p=0: x-path (q=0 self k<256, q=1 neigh k>=256); p=1: t-path (q=2/3)
__global__ __launch_bounds__(256) void k_b2t(const float* __restrict__ a2w, u16* __restrict__ b2t) {
  int idx = blockIdx.x * 256 + threadIdx.x;   // < 393216
  int c = idx / 131072; int rem = idx & 131071;
  int hp = rem >> 9; int k = rem & 511;
  int p = hp >> 7, h = hp & 127;
  int q = 2 * p + (k >= 256 ? 1 : 0);
  int kk = k & 255;
  b2t[idx] = f2b(a2w[(((c * 4 + q) * 128) + h) * 256 + kk]);
}

__global__ __launch_bounds__(256) void k_small(const float* __restrict__ a1b, const float* __restrict__ a2b,
    const float* __restrict__ s1w, const float* __restrict__ s2w,
    const float* __restrict__ pb1, const float* __restrict__ pb2, const float* __restrict__ pb3,
    float* __restrict__ sm) {
  int i = blockIdx.x * 256 + threadIdx.x;
  if (i < 768) {
    int c = i >> 8, j = i & 255;
    sm[i]        = a1b[(c * 4 + 0) * 256 + j] + a1b[(c * 4 + 1) * 256 + j];
    sm[768 + i]  = a1b[(c * 4 + 2) * 256 + j] + a1b[(c * 4 + 3) * 256 + j];
    sm[1536 + i] = sigm(s1w[i]);
  } else if (i < 1152) {
    int i2 = i - 768; int c = i2 >> 7, h = i2 & 127;
    sm[2304 + i2] = a2b[(c * 4 + 0) * 128 + h] + a2b[(c * 4 + 1) * 128 + h];
    sm[2688 + i2] = a2b[(c * 4 + 2) * 128 + h] + a2b[(c * 4 + 3) * 128 + h];
    sm[3072 + i2] = sigm(s2w[i2]);
  } else if (i < 1280) {
    int h = i - 1152;
    sm[3456 + h] = pb1[h] + pb2[h] + pb3[h];
  }
}

// ------------------------------ Z GEMM (one channel) -----------------------
// Z[M=100000][1024] = x[M][512](f32, cvt in-kernel) @ Bc[1024][512]^T (bf16)
// 128x128 tile, BK=64, 4 waves (2x2). A: reg-staged f32->bf16 with swizzled
// ds_write; B: global_load_lds w=16 with pre-inverse-swizzled source.
// Block mapping: m-fast within groups of 8 so each XCD's concurrent blocks
// share one A row-tile (L2 reuse).

__global__ __launch_bounds__(256) void k_zgemm(const float* __restrict__ A, const u16* __restrict__ B,
                                               u16* __restrict__ Zo) {
  __shared__ u16 As[128 * 64];
  __shared__ u16 Bs[128 * 64];
  const int tid = threadIdx.x;
  const int wid = tid >> 6, lane = tid & 63;
  int wg = blockIdx.x, mh, nh;          // 6256 blocks = 782 m-tiles x 8 n-tiles
  if (wg < 6208) { mh = (wg >> 6) * 8 + (wg & 7); nh = (wg >> 3) & 7; }
  else { int t = wg - 6208; mh = 776 + t % 6; nh = t / 6; }
  const int m0 = mh * 128, n0 = nh * 128;
  const int wm = (wid >> 1) * 64, wn = (wid & 1) * 64;
  f32x4 acc[4][4] = {};
  for (int kt = 0; kt < NF; kt += 64) {
    // B staging (async direct-to-LDS)
#pragma unroll
    for (int i = 0; i < 4; ++i) {
      const int chunk = (i * 4 + wid) * 64 + lane;
      const int row = chunk >> 3;
      const int slot = chunk & 7;
      const int sb = (slot << 4) ^ ((row & 7) << 4);   // inverse-swizzled source offset
      const char* gb = (const char*)(B + (size_t)(n0 + row) * NF + kt) + sb;
      gload_lds16(gb, Bs + (i * 4 + wid) * 512);
    }
    // A staging: f32 load -> bf16 -> swizzled ds_write
#pragma unroll
    for (int p = 0; p < 4; ++p) {
      const int cch = p * 256 + tid;      // 0..1023
      const int row = cch >> 3;
      const int k8 = cch & 7;
      int arow = m0 + row; arow = arow < NV ? arow : (NV - 1);
      const float* ga = A + (size_t)arow * NF + kt + k8 * 8;
      const f32x4 lo = *(const f32x4*)ga;
      const f32x4 hi = *(const f32x4*)(ga + 4);
      u16x8 pk;
      pk[0] = f2b(lo[0]); pk[1] = f2b(lo[1]); pk[2] = f2b(lo[2]); pk[3] = f2b(lo[3]);
      pk[4] = f2b(hi[0]); pk[5] = f2b(hi[1]); pk[6] = f2b(hi[2]); pk[7] = f2b(hi[3]);
      *(u16x8*)((char*)As + row * 128 + ((k8 << 4) ^ ((row & 7) << 4))) = pk;
    }
    asm volatile("s_waitcnt vmcnt(0)" ::: "memory");
    __syncthreads();
#pragma unroll
    for (int ks = 0; ks < 2; ++ks) {
      s16x8 af[4], bfr[4];
#pragma unroll
      for (int i = 0; i < 4; ++i) {
        const int ar = wm + i * 16 + (lane & 15);
        const int kb = ks * 64 + ((lane >> 4) << 4);
        af[i] = __builtin_bit_cast(s16x8,
            *(const u16x8*)((const char*)As + ar * 128 + (kb ^ ((ar & 7) << 4))));
        const int br = wn + i * 16 + (lane & 15);
        bfr[i] = __builtin_bit_cast(s16x8,
            *(const u16x8*)((const char*)Bs + br * 128 + (kb ^ ((br & 7) << 4))));
      }
#pragma unroll
      for (int mi = 0; mi < 4; ++mi)
#pragma unroll
        for (int ni = 0; ni < 4; ++ni)
          acc[mi][ni] = __builtin_amdgcn_mfma_f32_16x16x32_bf16(af[mi], bfr[ni], acc[mi][ni], 0, 0, 0);
    }
    __syncthreads();
  }
#pragma unroll
  for (int mi = 0; mi < 4; ++mi)
#pragma unroll
    for (int ni = 0; ni < 4; ++ni)
#pragma unroll
      for (int r = 0; r < 4; ++r) {
        const int row = m0 + wm + mi * 16 + (lane >> 4) * 4 + r;
        const int col = n0 + wn + ni * 16 + (lane & 15);
        if (row < NV) Zo[(size_t)row * ZC + col] = f2b(acc[mi][ni][r]);
      }
}

// ------------------- layer-1 fused over t-group (per channel) --------------
// one wave per row r; lanes cover 256 cols (4 each); v1 held in registers
// across up to 3 timesteps; outS written per slot.
__global__ __launch_bounds__(256) void k_l1f(const u16* __restrict__ Z, const int* __restrict__ nodes,
    const int* __restrict__ nbr1, const int* __restrict__ nbr2,
    float* __restrict__ v1g, u16* __restrict__ outS, const float* __restrict__ sm,
    int c, int t0, int t1, int t2, int nts, int loadv, int savev) {
  const int r = blockIdx.x * 4 + (threadIdx.x >> 6);
  const int lane = threadIdx.x & 63;
  const int j = lane * 4;
  const int rr = r - NN;

  const f32x4 bx = *(const f32x4*)(sm + c * 256 + j);
  const f32x4 bt = *(const f32x4*)(sm + 768 + c * 256 + j);
  const f32x4 sw = *(const f32x4*)(sm + 1536 + c * 256 + j);
  const size_t vo = (size_t)r * 256 + j;
  f32x4 v;
  if (loadv) v = *(const f32x4*)(v1g + vo);
  else { v[0] = 0.f; v[1] = 0.f; v[2] = 0.f; v[3] = 0.f; }

  // self embedding is t-invariant only for the h0 rows (r < NN)
  u16x4 sx0, st0;
  if (r < NN) {
    const size_t zb = (size_t)nodes[r] * ZC;
    sx0 = *(const u16x4*)(Z + zb + j);
    st0 = *(const u16x4*)(Z + zb + 512 + j);
  }

  for (int s = 0; s < nts; ++s) {
    const int t = (s == 0) ? t0 : ((s == 1) ? t1 : t2);
    const int* n1 = nbr1 + t * (NN * 5);
    const int* n2 = nbr2 + t * (NN * 10);
    u16x4 sx, st;
    float nx[4] = {0.f, 0.f, 0.f, 0.f}, ntv[4] = {0.f, 0.f, 0.f, 0.f};
    float inv;
    if (r < NN) {
      sx = sx0; st = st0; inv = 0.2f;
      int nb[5];
#pragma unroll
      for (int q = 0; q < 5; ++q) nb[q] = n1[r * 5 + q];
#pragma unroll
      for (int q = 0; q < 5; ++q) {
        const size_t zn = (size_t)nb[q] * ZC;
        const u16x4 qx = *(const u16x4*)(Z + zn + 256 + j);
        const u16x4 qt = *(const u16x4*)(Z + zn + 768 + j);
#pragma unroll
        for (int e = 0; e < 4; ++e) { nx[e] += b2f(qx[e]); ntv[e] += b2f(qt[e]); }
      }
    } else {
      inv = 0.5f;
      const size_t zb = (size_t)n1[rr] * ZC;
      sx = *(const u16x4*)(Z + zb + j);
      st = *(const u16x4*)(Z + zb + 512 + j);
      const int nb0 = n2[rr * 2], nb1 = n2[rr * 2 + 1];
#pragma unroll
      for (int q = 0; q < 2; ++q) {
        const size_t zn = (size_t)(q == 0 ? nb0 : nb1) * ZC;
        const u16x4 qx = *(const u16x4*)(Z + zn + 256 + j);
        const u16x4 qt = *(const u16x4*)(Z + zn + 768 + j);
#pragma unroll
        for (int e = 0; e < 4; ++e) { nx[e] += b2f(qx[e]); ntv[e] += b2f(qt[e]); }
      }
    }
    u16x4 os;
#pragma unroll
    for (int e = 0; e < 4; ++e) {
      const float ox = b2f(sx[e]) + nx[e] * inv + bx[e];
      const float ot = b2f(st[e]) + ntv[e] * inv + bt[e];
      const float vv = sw[e] * v[e] + ot;
      const float sp = (vv >= 1.0f) ? 1.0f : 0.0f;
      v[e] = vv - sp;
      os[e] = f2b(sp * sigm(ox));
    }
    *(u16x4*)(outS + (size_t)s * SLICE + (size_t)r * 256 + j) = os;
  }
  if (savev) *(f32x4*)(v1g + vo) = v;
}

// ------------------- layer-2 fused over t-group (per channel) --------------
// per block: 16 nodes x 256 outputs; per slot: stage A=[h0b | mean5(h1b)] in
// LDS (swizzled), MFMA, BLIF2+pool epilogue with v2/eacc in registers.
__global__ __launch_bounds__(256) void k_l2f(const u16* __restrict__ outS, const u16* __restrict__ B2t,
    float* __restrict__ v2, float* __restrict__ eacc, const float* __restrict__ sm,
    const float* __restrict__ pw, int Tc, int tixb, int nts, int c, int loadv, int savev) {
  __shared__ u16 As[16 * 512];
  const int tid = threadIdx.x, lane = tid & 63, w = tid >> 6;
  const int n0 = blockIdx.x * 16;

  // per-thread output coordinates: (f in 0..1) x (r in 0..3)
  int hh[2], nn_[4];
#pragma unroll
  for (int f = 0; f < 2; ++f) hh[f] = 32 * w + 16 * f + (lane & 15);
#pragma unroll
  for (int r = 0; r < 4; ++r) nn_[r] = n0 + (lane >> 4) * 4 + r;

  float v2r[8], er[8];
#pragma unroll
  for (int f = 0; f < 2; ++f)
#pragma unroll
    for (int r = 0; r < 4; ++r) {
      const size_t gi = (size_t)nn_[r] * 128 + hh[f];
      v2r[f * 4 + r] = loadv ? v2[gi] : 0.f;
      er[f * 4 + r] = eacc[gi];
    }
  float bxv[2], btv[2], swv[2];
#pragma unroll
  for (int f = 0; f < 2; ++f) {
    bxv[f] = sm[2304 + c * 128 + hh[f]];
    btv[f] = sm[2688 + c * 128 + hh[f]];
    swv[f] = sm[3072 + c * 128 + hh[f]];
  }
  const u16* Bc = B2t + (size_t)c * 256 * 512;
  const int nbase[4] = {32 * w, 32 * w + 16, 128 + 32 * w, 128 + 32 * w + 16};

  for (int s = 0; s < nts; ++s) {
    if (s) __syncthreads();
    const u16* oc = outS + (size_t)s * SLICE;
    {
      const int row = tid >> 4;
      const int k0 = (tid & 15) * 32;
#pragma unroll
      for (int g = 0; g < 4; ++g) {
        const int k = k0 + g * 8;
        u16x8 pk;
        if (k < 256) {
          pk = *(const u16x8*)(oc + (size_t)(n0 + row) * 256 + k);
        } else {
          float a[8] = {0.f,0.f,0.f,0.f,0.f,0.f,0.f,0.f};
#pragma unroll
          for (int q = 0; q < 5; ++q) {
            const u16x8 qv = *(const u16x8*)(oc + (size_t)(NN + (size_t)(n0 + row) * 5 + q) * 256 + (k - 256));
#pragma unroll
            for (int e = 0; e < 8; ++e) a[e] += b2f(qv[e]);
          }
#pragma unroll
          for (int e = 0; e < 8; ++e) pk[e] = f2b(a[e] * 0.2f);
        }
        *(u16x8*)((char*)As + row * 1024 + ((k * 2) ^ ((row & 7) << 4))) = pk;
      }
    }
    __syncthreads();
    f32x4 acc[4] = {};
#pragma unroll
    for (int ks = 0; ks < 16; ++ks) {
      const int ar = lane & 15;
      const int kb = ks * 64 + ((lane >> 4) << 4);
      const s16x8 af = __builtin_bit_cast(s16x8,
          *(const u16x8*)((const char*)As + ar * 1024 + (kb ^ ((ar & 7) << 4))));
#pragma unroll
      for (int f = 0; f < 4; ++f) {
        const u16* bp = Bc + (size_t)(nbase[f] + (lane & 15)) * 512 + ks * 32 + ((lane >> 4) << 3);
        const s16x8 bv = __builtin_bit_cast(s16x8, *(const u16x8*)bp);
        acc[f] = __builtin_amdgcn_mfma_f32_16x16x32_bf16(af, bv, acc[f], 0, 0, 0);
      }
    }
#pragma unroll
    for (int f = 0; f < 2; ++f) {
      const float pw0 = pw[hh[f] * Tc + tixb + s];
#pragma unroll
      for (int r = 0; r < 4; ++r) {
        const int idx = f * 4 + r;
        const float ox = acc[f][r] + bxv[f];
        const float ot = acc[f + 2][r] + btv[f];
        const float vv = swv[f] * v2r[idx] + ot;
        const float sp = (vv >= 1.0f) ? 1.0f : 0.0f;
        v2r[idx] = vv - sp;
        if (sp > 0.0f) er[idx] += sigm(ox) * pw0;
      }
    }
  }
#pragma unroll
  for (int f = 0; f < 2; ++f)
#pragma unroll
    for (int r = 0; r < 4; ++r) {
      const size_t gi = (size_t)nn_[r] * 128 + hh[f];
      eacc[gi] = er[f * 4 + r];
      if (savev) v2[gi] = v2r[f * 4 + r];
    }
}

// ------------------------------- final -------------------------------------
__global__ __launch_bounds__(256) void k_final(const float* __restrict__ eacc, const float* __restrict__ sm,
    const float* __restrict__ mtgw, const float* __restrict__ mtgb, float* __restrict__ out) {
  const int idx = blockIdx.x * 256 + threadIdx.x;   // exactly 16384*40
  const int n = idx / NC, k = idx % NC;
  const float* e0 = eacc + (size_t)n * 128;
  const float* pb = sm + 3456;
  const float* mw = mtgw + k * 128;
  float accv = 0.0f;
  for (int h = 0; h < 128; ++h) {
    const float emb = (e0[h] + pb[h]) * (1.0f / 3.0f);
    accv += emb * mw[h];
  }
  out[idx] = accv + mtgb[k];
}

// ------------------------------- launch ------------------------------------
extern "C" void kernel_launch(void* const* d_in, const int* in_sizes, int n_in,
                              void* d_out, int out_size, void* d_ws, size_t ws_size,
                              hipStream_t stream) {
  (void)in_sizes; (void)n_in; (void)out_size;
  if (ws_size < OFF_END) return;

  const float* x    = (const float*)d_in[0];
  const float* a1w  = (const float*)d_in[1];
  const float* a1b  = (const float*)d_in[2];
  const float* a2w  = (const float*)d_in[3];
  const float* a2b  = (const float*)d_in[4];
  const float* s1w  = (const float*)d_in[5];
  const float* s2w  = (const float*)d_in[6];
  const float* pw1  = (const float*)d_in[7];
  const float* pb1  = (const float*)d_in[8];
  const float* pw2  = (const float*)d_in[9];
  const float* pb2  = (const float*)d_in[10];
  const float* pw3  = (const float*)d_in[11];
  const float* pb3  = (const float*)d_in[12];
  const float* mtgw = (const float*)d_in[13];
  const float* mtgb = (const float*)d_in[14];
  const int* nodes  = (const int*)d_in[15];
  const int* nbr1   = (const int*)d_in[16];
  const int* nbr2   = (const int*)d_in[17];

  char* w = (char*)d_ws;
  u16* b1t   = (u16*)(w + OFF_B1T);
  u16* b2t   = (u16*)(w + OFF_B2T);
  float* sm  = (float*)(w + OFF_SM);
  u16* z     = (u16*)(w + OFF_Z);
  float* v1  = (float*)(w + OFF_V1);
  float* v2  = (float*)(w + OFF_V2);
  float* eacc= (float*)(w + OFF_EACC);
  u16* outS  = (u16*)(w + OFF_OUTS);

  k_cast<<<1536, 256, 0, stream>>>(a1w, b1t, 393216);
  k_b2t<<<1536, 256, 0, stream>>>(a2w, b2t);
  k_small<<<5, 256, 0, stream>>>(a1b, a2b, s1w, s2w, pb1, pb2, pb3, sm);
  k_zero<<<512, 256, 0, stream>>>(eacc, 524288);

  // channel 0: t = {0,1,2} then {3,4,5}; Tc=6
  k_zgemm<<<6256, 256, 0, stream>>>(x, b1t, z);
  k_l1f<<<24576, 256, 0, stream>>>(z, nodes, nbr1, nbr2, v1, outS, sm, 0, 0, 1, 2, 3, 0, 1);
  k_l2f<<<1024, 256, 0, stream>>>(outS, b2t, v2, eacc, sm, pw1, 6, 0, 3, 0, 0, 1);
  k_l1f<<<24576, 256, 0, stream>>>(z, nodes, nbr1, nbr2, v1, outS, sm, 0, 3, 4, 5, 3, 1, 0);
  k_l2f<<<1024, 256, 0, stream>>>(outS, b2t, v2, eacc, sm, pw1, 6, 3, 3, 0, 1, 0);

  // channel 1: t = {0,2,4}; Tc=3
  k_zgemm<<<6256, 256, 0, stream>>>(x, b1t + 524288, z);
  k_l1f<<<24576, 256, 0, stream>>>(z, nodes, nbr1, nbr2, v1, outS, sm, 1, 0, 2, 4, 3, 0, 0);
  k_l2f<<<1024, 256, 0, stream>>>(outS, b2t, v2, eacc, sm, pw2, 3, 0, 3, 1, 0, 0);

  // channel 2: t = {2,5}; Tc=2
  k_zgemm<<<6256, 256, 0, stream>>>(x, b1t + 1048576, z);
  k_l1f<<<24576, 256, 0, stream>>>(z, nodes, nbr1, nbr2, v1, outS, sm, 2, 2, 5, 0, 2, 0, 0);
  k_l2f<<<1024, 256, 0, stream>>>(outS, b2t, v2, eacc, sm, pw3, 2, 0, 2, 2, 0, 0);

  k_final<<<2560, 256, 0, stream>>>(eacc, sm, mtgw, mtgb, (float*)d_out);
}